// Round 1
// baseline (25.795 us; speedup 1.0000x reference)
//
#include <hip/hip_runtime.h>

#define BATCH 4
#define NB    256
#define NE    (NB*(NB-1))   // 65280
#define FIN   64
#define HD    64

typedef short  short8  __attribute__((ext_vector_type(8)));
typedef float  f32x16  __attribute__((ext_vector_type(16)));

__device__ __forceinline__ short f2bf(float x) {
    unsigned u = __builtin_bit_cast(unsigned, x);
    u += 0x7fffu + ((u >> 16) & 1u);   // round-to-nearest-even
    return (short)(u >> 16);
}

// ---------------------------------------------------------------------------
// Kernel 1: per-node projections + weight swizzles.
//   Psw [2][B][8][N][8]  : P[i,b,n,h] = x[b,n,:]·W1[i][:64,h]  (fragment layout)
//   Q   [2][B][N][64]    : x[b,n,:]·W1[i][64:,h] + b1[i][h]
//   W2f [2][2][4][64][8] : bf16 B-fragments of W2 for mfma_32x32x16
// ---------------------------------------------------------------------------
__global__ __launch_bounds__(64) void prep_kernel(
    const float* __restrict__ x,   // [B][N][F]
    const float* __restrict__ W1,  // [2][128][64]
    const float* __restrict__ b1,  // [2][64]
    const float* __restrict__ W2,  // [2][64][64]
    float* __restrict__ Psw,
    float* __restrict__ Q,
    short* __restrict__ W2f)
{
    const int blk = blockIdx.x;
    const int t   = threadIdx.x;
    __shared__ float xl[FIN];

    if (blk < 2 * BATCH * NB) {
        const int i   = blk >> 10;       // edge type
        const int rem = blk & 1023;
        const int b   = rem >> 8;
        const int n   = rem & 255;
        xl[t] = x[(b * NB + n) * FIN + t];
        __syncthreads();
        const float* w1s = W1 + i * 128 * 64;            // sender rows 0..63
        const float* w1r = W1 + i * 128 * 64 + 64 * 64;  // receiver rows 64..127
        float accP = 0.f;
        float accQ = b1[i * 64 + t];
        #pragma unroll 8
        for (int f = 0; f < 64; ++f) {
            float xv = xl[f];
            accP = fmaf(xv, w1s[f * 64 + t], accP);
            accQ = fmaf(xv, w1r[f * 64 + t], accQ);
        }
        Psw[(((i * BATCH + b) * 8 + (t >> 3)) * NB + n) * 8 + (t & 7)] = accP;
        Q[((i * BATCH + b) * NB + n) * 64 + t] = accQ;
    } else {
        // single extra block: swizzle W2 into bf16 B-fragments
        #pragma unroll
        for (int i = 0; i < 2; ++i)
            #pragma unroll
            for (int nt = 0; nt < 2; ++nt)
                #pragma unroll
                for (int k0 = 0; k0 < 4; ++k0)
                    #pragma unroll
                    for (int j = 0; j < 8; ++j) {
                        int k = k0 * 16 + 8 * (t >> 5) + j;
                        int n = (t & 31) + 32 * nt;
                        W2f[(((i * 2 + nt) * 4 + k0) * 64 + t) * 8 + j] =
                            f2bf(W2[(i * 64 + k) * 64 + n]);
                    }
    }
}

// ---------------------------------------------------------------------------
// Kernel 2: one workgroup per (b, receiver r). 256 threads = 4 waves.
// Wave w owns edge rows [64w, 64w+64). Computes msg2 = relu(msg1@W2+b2),
// weights by rel_type, row-reduces to agg[b,r,:], then fused output MLP.
// ---------------------------------------------------------------------------
__global__ __launch_bounds__(256) void main_kernel(
    const float* __restrict__ x,
    const float* __restrict__ rel_type, // [B][E][2]
    const float* __restrict__ b2,       // [2][64]
    const float* __restrict__ Wo1,      // [128][64]
    const float* __restrict__ bo1,      // [64]
    const float* __restrict__ Wo2,      // [64][64]
    const float* __restrict__ bo2,      // [64]
    const float* __restrict__ Psw,
    const float* __restrict__ Q,
    const short* __restrict__ W2f,
    float* __restrict__ out)
{
    const int b = blockIdx.x >> 8;
    const int r = blockIdx.x & 255;
    const int t = threadIdx.x;
    const int lane = t & 63;
    const int w    = t >> 6;

    __shared__ __align__(16) float rt[256][2];
    __shared__ __align__(16) float qrow[2][64];
    __shared__ __align__(16) float b2l[2][64];
    __shared__ __align__(16) float red[4][64];
    __shared__ __align__(16) float aggl[64];
    __shared__ __align__(16) float xl[64];
    __shared__ __align__(16) float predl[64];

    // ---- stage per-wg data ----
    if (t < 255) {
        const float* p = rel_type + ((size_t)b * NE + (size_t)r * 255 + t) * 2;
        rt[t][0] = p[0];
        rt[t][1] = p[1];
    } else if (t == 255) {
        rt[255][0] = 0.f; rt[255][1] = 0.f;   // padding row contributes 0
    }
    if (t < 128) {
        int i = t >> 6, h = t & 63;
        qrow[i][h] = Q[((i * BATCH + b) * NB + r) * 64 + h];
        b2l[i][h]  = b2[i * 64 + h];
    }
    if (t < 64) xl[t] = x[(b * NB + r) * FIN + t];
    __syncthreads();

    const int l31 = lane & 31;
    const int lh  = lane >> 5;        // 0/1

    // edge rows (local k) for this wave's two M-tiles
    const int k0m = 64 * w + l31;
    const int k1m = 64 * w + 32 + l31;
    int s0 = (k0m < r) ? k0m : k0m + 1; if (s0 > 255) s0 = 255;  // k=255 pad
    int s1 = (k1m < r) ? k1m : k1m + 1; if (s1 > 255) s1 = 255;

    float psum0 = 0.f, psum1 = 0.f;   // per-lane partial agg, cols l31 / l31+32

    #pragma unroll
    for (int i = 0; i < 2; ++i) {
        const float* Pb = Psw + (size_t)(i * BATCH + b) * 8 * NB * 8;
        const short* wf = W2f + (size_t)i * 2 * 4 * 64 * 8;

        short8 Bf[2][4];
        #pragma unroll
        for (int nt = 0; nt < 2; ++nt)
            #pragma unroll
            for (int k0 = 0; k0 < 4; ++k0)
                Bf[nt][k0] = *(const short8*)(wf + ((nt * 4 + k0) * 64 + lane) * 8);

        f32x16 acc00 = {}, acc01 = {}, acc10 = {}, acc11 = {};

        #pragma unroll
        for (int k0 = 0; k0 < 4; ++k0) {
            const int hb = 2 * k0 + lh;
            const int h0 = hb * 8;
            float4 pa0 = *(const float4*)(Pb + (hb * NB + s0) * 8);
            float4 pa1 = *(const float4*)(Pb + (hb * NB + s0) * 8 + 4);
            float4 pb0 = *(const float4*)(Pb + (hb * NB + s1) * 8);
            float4 pb1 = *(const float4*)(Pb + (hb * NB + s1) * 8 + 4);
            float4 q0  = *(const float4*)(&qrow[i][h0]);
            float4 q1  = *(const float4*)(&qrow[i][h0 + 4]);

            short8 a0, a1;
            a0[0] = f2bf(fmaxf(pa0.x + q0.x, 0.f));
            a0[1] = f2bf(fmaxf(pa0.y + q0.y, 0.f));
            a0[2] = f2bf(fmaxf(pa0.z + q0.z, 0.f));
            a0[3] = f2bf(fmaxf(pa0.w + q0.w, 0.f));
            a0[4] = f2bf(fmaxf(pa1.x + q1.x, 0.f));
            a0[5] = f2bf(fmaxf(pa1.y + q1.y, 0.f));
            a0[6] = f2bf(fmaxf(pa1.z + q1.z, 0.f));
            a0[7] = f2bf(fmaxf(pa1.w + q1.w, 0.f));
            a1[0] = f2bf(fmaxf(pb0.x + q0.x, 0.f));
            a1[1] = f2bf(fmaxf(pb0.y + q0.y, 0.f));
            a1[2] = f2bf(fmaxf(pb0.z + q0.z, 0.f));
            a1[3] = f2bf(fmaxf(pb0.w + q0.w, 0.f));
            a1[4] = f2bf(fmaxf(pb1.x + q1.x, 0.f));
            a1[5] = f2bf(fmaxf(pb1.y + q1.y, 0.f));
            a1[6] = f2bf(fmaxf(pb1.z + q1.z, 0.f));
            a1[7] = f2bf(fmaxf(pb1.w + q1.w, 0.f));

            acc00 = __builtin_amdgcn_mfma_f32_32x32x16_bf16(a0, Bf[0][k0], acc00, 0, 0, 0);
            acc01 = __builtin_amdgcn_mfma_f32_32x32x16_bf16(a0, Bf[1][k0], acc01, 0, 0, 0);
            acc10 = __builtin_amdgcn_mfma_f32_32x32x16_bf16(a1, Bf[0][k0], acc10, 0, 0, 0);
            acc11 = __builtin_amdgcn_mfma_f32_32x32x16_bf16(a1, Bf[1][k0], acc11, 0, 0, 0);
        }

        // ---- epilogue: bias, relu, rel_type weight, row-reduce ----
        const float b2v0 = b2l[i][l31];
        const float b2v1 = b2l[i][l31 + 32];
        #pragma unroll
        for (int reg = 0; reg < 16; ++reg) {
            const int rowoff = (reg & 3) + 8 * (reg >> 2) + 4 * lh;
            const float rt0 = rt[64 * w + rowoff][i];
            const float rt1 = rt[64 * w + 32 + rowoff][i];
            psum0 += fmaxf(acc00[reg] + b2v0, 0.f) * rt0;
            psum1 += fmaxf(acc01[reg] + b2v1, 0.f) * rt0;
            psum0 += fmaxf(acc10[reg] + b2v0, 0.f) * rt1;
            psum1 += fmaxf(acc11[reg] + b2v1, 0.f) * rt1;
        }
    }

    // ---- reduce: lane-halves, then waves ----
    psum0 += __shfl_xor(psum0, 32, 64);
    psum1 += __shfl_xor(psum1, 32, 64);
    if ((lane & 32) == 0) {
        red[w][l31]      = psum0;
        red[w][l31 + 32] = psum1;
    }
    __syncthreads();
    if (t < 64) aggl[t] = red[0][t] + red[1][t] + red[2][t] + red[3][t];
    __syncthreads();

    // ---- output MLP layer 1: aug(128) @ Wo1(128x64) ----
    {
        const int h = t & 63, part = t >> 6;
        const int j0 = part * 32;
        float s = 0.f;
        #pragma unroll 8
        for (int jj = 0; jj < 32; ++jj) {
            const int j = j0 + jj;
            const float a = (j < 64) ? xl[j] : aggl[j - 64];
            s = fmaf(a, Wo1[j * 64 + h], s);
        }
        red[part][h] = s;
    }
    __syncthreads();
    if (t < 64) {
        float s = red[0][t] + red[1][t] + red[2][t] + red[3][t] + bo1[t];
        predl[t] = fmaxf(s, 0.f);
    }
    __syncthreads();

    // ---- output MLP layer 2 + residual ----
    {
        const int h = t & 63, part = t >> 6;
        const int j0 = part * 16;
        float s = 0.f;
        #pragma unroll 8
        for (int jj = 0; jj < 16; ++jj) {
            const int j = j0 + jj;
            s = fmaf(predl[j], Wo2[j * 64 + h], s);
        }
        red[part][h] = s;
    }
    __syncthreads();
    if (t < 64) {
        float s = red[0][t] + red[1][t] + red[2][t] + red[3][t] + bo2[t];
        out[((size_t)b * NB + r) * 64 + t] = xl[t] + fmaxf(s, 0.f);
    }
}

// ---------------------------------------------------------------------------
extern "C" void kernel_launch(void* const* d_in, const int* in_sizes, int n_in,
                              void* d_out, int out_size, void* d_ws, size_t ws_size,
                              hipStream_t stream) {
    (void)in_sizes; (void)n_in; (void)out_size; (void)ws_size;

    const float* x    = (const float*)d_in[0];
    const float* rt   = (const float*)d_in[1];
    // d_in[2] = rel_rec, d_in[3] = rel_send: one-hot all-pairs structure, unused
    const float* W1   = (const float*)d_in[4];
    const float* b1   = (const float*)d_in[5];
    const float* W2   = (const float*)d_in[6];
    const float* b2   = (const float*)d_in[7];
    const float* Wo1  = (const float*)d_in[8];
    const float* bo1  = (const float*)d_in[9];
    const float* Wo2  = (const float*)d_in[10];
    const float* bo2  = (const float*)d_in[11];
    float* out = (float*)d_out;

    char* ws = (char*)d_ws;
    float* Psw = (float*)ws;                 // 2*4*8*256*8*4B = 512 KiB
    float* Q   = (float*)(ws + 524288);      // 512 KiB
    short* W2f = (short*)(ws + 1048576);     // 16 KiB

    prep_kernel<<<2 * BATCH * NB + 1, 64, 0, stream>>>(x, W1, b1, W2, Psw, Q, W2f);
    main_kernel<<<BATCH * NB, 256, 0, stream>>>(x, rt, b2, Wo1, bo1, Wo2, bo2,
                                                Psw, Q, W2f, out);
}